// Round 6
// baseline (177.401 us; speedup 1.0000x reference)
//
#include <hip/hip_runtime.h>
#include <cstddef>

// Problem constants (match reference)
constexpr int Bn = 16384;
constexpr int Sn = 32;
constexpr int Dn = 64;

// ---------- within-16-lane sum via DPP (identical order to xor1/2/4/8 tree) ----
__device__ __forceinline__ float dpp_add(float v, const int ctrl) {
    int t;
    switch (ctrl) {  // ctrl must be a literal constant for the builtin
        case 0xB1:  t = __builtin_amdgcn_update_dpp(0, __builtin_bit_cast(int, v), 0xB1, 0xF, 0xF, true); break;
        case 0x4E:  t = __builtin_amdgcn_update_dpp(0, __builtin_bit_cast(int, v), 0x4E, 0xF, 0xF, true); break;
        case 0x141: t = __builtin_amdgcn_update_dpp(0, __builtin_bit_cast(int, v), 0x141, 0xF, 0xF, true); break;
        default:    t = __builtin_amdgcn_update_dpp(0, __builtin_bit_cast(int, v), 0x140, 0xF, 0xF, true); break;
    }
    return v + __builtin_bit_cast(float, t);
}

__device__ __forceinline__ float red16_dpp(float v) {
    v = dpp_add(v, 0xB1);   // quad_perm [1,0,3,2]  == xor 1
    v = dpp_add(v, 0x4E);   // quad_perm [2,3,0,1]  == xor 2
    v = dpp_add(v, 0x141);  // row_half_mirror      (== xor 4 once quad-uniform)
    v = dpp_add(v, 0x140);  // row_mirror           (== xor 8 once 8-uniform)
    return v;
}

// 2 waves per row: wave pair (wave^1). Each wave owns 16 of the 32 slots.
__global__ __launch_bounds__(256, 6) void amem_fwd(
    const float* __restrict__ gw_r, const float* __restrict__ gw_i,
    const float* __restrict__ mem_r, const float* __restrict__ mem_i,
    const float* __restrict__ Wg,   const float* __restrict__ bg,
    const float* __restrict__ Wa,   const float* __restrict__ ba,
    const float* __restrict__ g_r,  const float* __restrict__ b_r,
    const float* __restrict__ g_i,  const float* __restrict__ b_i,
    float* __restrict__ o_read_r, float* __restrict__ o_read_i,
    float* __restrict__ o_next_r, float* __restrict__ o_next_i,
    float* __restrict__ ws_ent)
{
    __shared__ float sWa[4096];        // Wa staged once per block: [128][32] row-major
    __shared__ float lflat[4][128];    // per-wave [gw_r; gw_i] broadcast
    __shared__ float xmax[4];          // per-wave softmax partials
    __shared__ float xsum[4];
    __shared__ float4 xchR[4][16];     // per-wave read-vector partials
    __shared__ float4 xchI[4][16];

    const int tid  = threadIdx.x;
    const int wave = tid >> 6;       // 4 waves/block = 2 rows
    const int l    = tid & 63;
    const int h2   = wave & 1;       // which half of the slots this wave owns
    const int b    = blockIdx.x * 2 + (wave >> 1);
    const int g    = l >> 4;         // slot-subgroup 0..3
    const int q    = l & 15;         // d0 = q*4
    const int sl   = l & 31;
    const int h    = l >> 5;

    const float4 q4r = ((const float4*)gw_r)[b * 16 + q];
    const float4 q4i = ((const float4*)gw_i)[b * 16 + q];

    // ---- stage Wa into LDS (block-wide, once) + flat broadcast ----
    {
        const float4* Wa4 = (const float4*)Wa;
        float4* sWa4 = (float4*)sWa;
#pragma unroll
        for (int j = 0; j < 4; ++j) sWa4[tid + 256 * j] = Wa4[tid + 256 * j];
    }
    if (g == 0)      *(float4*)&lflat[wave][q * 4]      = q4r;
    else if (g == 1) *(float4*)&lflat[wave][64 + q * 4] = q4i;

    // ---- issue this half-row's mem loads NOW; middle section hides latency ----
    // lane l, iter k holds float4 at (s = h2*16 + k*4 + g, d = q*4..q*4+3)
    const float4* mr4 = (const float4*)mem_r + (size_t)b * 512 + h2 * 256;
    const float4* mi4 = (const float4*)mem_i + (size_t)b * 512 + h2 * 256;
    float4 m_r[4], m_i[4];
#pragma unroll
    for (int k = 0; k < 4; ++k) {
        m_r[k] = mr4[k * 64 + l];
        m_i[k] = mi4[k * 64 + l];
    }

    __syncthreads();   // sWa + lflat visible

    // ================= middle section (gw-only; duplicated across the pair) ====
    const float4 wg0 = ((const float4*)Wg)[q];
    const float4 wg1 = ((const float4*)Wg)[16 + q];
    float wp = q4r.x * wg0.x + q4r.y * wg0.y + q4r.z * wg0.z + q4r.w * wg0.w
             + q4i.x * wg1.x + q4i.y * wg1.y + q4i.z * wg1.z + q4i.w * wg1.w;
    wp = red16_dpp(wp);
    const float wgate = 1.0f / (1.0f + __expf(-(wp + bg[0])));

    // logits = [gw_r;gw_i] @ Wa + ba (Wa from LDS, 4 independent accumulators)
    const float* WaL = sWa + h * 2048;
    const float4* lf4 = (const float4*)&lflat[wave][h * 64];
    float a0 = 0.f, a1 = 0.f, a2 = 0.f, a3 = 0.f;
#pragma unroll
    for (int jj = 0; jj < 16; ++jj) {
        const float4 f = lf4[jj];
        const int r0 = jj * 4;
        a0 = fmaf(f.x, WaL[(r0 + 0) * 32 + sl], a0);
        a1 = fmaf(f.y, WaL[(r0 + 1) * 32 + sl], a1);
        a2 = fmaf(f.z, WaL[(r0 + 2) * 32 + sl], a2);
        a3 = fmaf(f.w, WaL[(r0 + 3) * 32 + sl], a3);
    }
    float acc = (a0 + a1) + (a2 + a3);
    acc += __shfl_xor(acc, 32);   // combine real/imag halves
    acc += ba[sl];

    // softmax over 32 slots (within each 32-lane half; halves identical)
    float lm = acc;
    lm = fmaxf(lm, __shfl_xor(lm, 1));
    lm = fmaxf(lm, __shfl_xor(lm, 2));
    lm = fmaxf(lm, __shfl_xor(lm, 4));
    lm = fmaxf(lm, __shfl_xor(lm, 8));
    lm = fmaxf(lm, __shfl_xor(lm, 16));
    const float we = __expf(acc - lm);
    float wsum = we;
    wsum += __shfl_xor(wsum, 1);
    wsum += __shfl_xor(wsum, 2);
    wsum += __shfl_xor(wsum, 4);
    wsum += __shfl_xor(wsum, 8);
    wsum += __shfl_xor(wsum, 16);
    const float ww = we / wsum;

    // entropy partial (one wave of the pair writes)
    float et = ww * __logf(ww + 1e-10f);
    et += __shfl_xor(et, 1);
    et += __shfl_xor(et, 2);
    et += __shfl_xor(et, 4);
    et += __shfl_xor(et, 8);
    et += __shfl_xor(et, 16);
    if (h2 == 0 && l == 0) ws_ent[b] = -et;

    // top-3 via 3 argmax butterflies (value desc, index asc on ties)
    float lv = ww;
    float v1, v2, v3;
    int   i1, i2, i3;
#pragma unroll
    for (int pass = 0; pass < 3; ++pass) {
        float bv = lv;
        int   bi = sl;
#pragma unroll
        for (int d = 1; d <= 16; d <<= 1) {
            const float ov = __shfl_xor(bv, d);
            const int   oi = __shfl_xor(bi, d);
            if (ov > bv || (ov == bv && oi < bi)) { bv = ov; bi = oi; }
        }
        if (pass == 0) { v1 = bv; i1 = bi; }
        else if (pass == 1) { v2 = bv; i2 = bi; }
        else { v3 = bv; i3 = bi; }
        if (sl == bi) lv = -1.f;
    }
    const float inv_ssum = 1.0f / (v1 + v2 + v3 + 1e-6f);

    // ================= sim over this wave's 16 slots + paired softmax ========
    float sims[4];
#pragma unroll
    for (int k = 0; k < 4; ++k) {
        float p = m_r[k].x * q4r.x + m_r[k].y * q4r.y + m_r[k].z * q4r.z + m_r[k].w * q4r.w
                + m_i[k].x * q4i.x + m_i[k].y * q4i.y + m_i[k].z * q4i.z + m_i[k].w * q4i.w;
        sims[k] = red16_dpp(p);
    }
    float mx = fmaxf(fmaxf(sims[0], sims[1]), fmaxf(sims[2], sims[3]));
    mx = fmaxf(mx, __shfl_xor(mx, 16));
    mx = fmaxf(mx, __shfl_xor(mx, 32));
    if (l == 0) xmax[wave] = mx;
    __syncthreads();
    mx = fmaxf(mx, xmax[wave ^ 1]);

    float attn[4];
    float asum = 0.f;
#pragma unroll
    for (int k = 0; k < 4; ++k) { attn[k] = __expf(sims[k] - mx); asum += attn[k]; }
    asum += __shfl_xor(asum, 16);
    asum += __shfl_xor(asum, 32);
    if (l == 0) xsum[wave] = asum;
    __syncthreads();
    asum += xsum[wave ^ 1];
    const float ainv = 1.0f / asum;
#pragma unroll
    for (int k = 0; k < 4; ++k) attn[k] *= ainv;

    // ================= blend + dual LayerNorm, r then i (low reg pressure) ====
    float4* onr = (float4*)o_next_r + (size_t)b * 512 + h2 * 256;
    float4* oni = (float4*)o_next_i + (size_t)b * 512 + h2 * 256;
    float4 rr = {0.f, 0.f, 0.f, 0.f}, ri = {0.f, 0.f, 0.f, 0.f};

    {   // ---- real part ----
        const float4 gr = ((const float4*)g_r)[q];
        const float4 br = ((const float4*)b_r)[q];
#pragma unroll
        for (int k = 0; k < 4; ++k) {
            rr.x = fmaf(attn[k], m_r[k].x, rr.x); rr.y = fmaf(attn[k], m_r[k].y, rr.y);
            rr.z = fmaf(attn[k], m_r[k].z, rr.z); rr.w = fmaf(attn[k], m_r[k].w, rr.w);

            const int s = h2 * 16 + k * 4 + g;
            const float sp = (s == i1) ? v1 : (s == i2) ? v2 : (s == i3) ? v3 : 0.f;
            const float eu = wgate * sp * inv_ssum;
            const float om = 1.f - eu;

            float4 x;
            x.x = om * m_r[k].x + eu * q4r.x;
            x.y = om * m_r[k].y + eu * q4r.y;
            x.z = om * m_r[k].z + eu * q4r.z;
            x.w = om * m_r[k].w + eu * q4r.w;

            float sr = (x.x + x.y) + (x.z + x.w);
            float qr = x.x * x.x; qr = fmaf(x.y, x.y, qr); qr = fmaf(x.z, x.z, qr); qr = fmaf(x.w, x.w, qr);
            sr = red16_dpp(sr);
            qr = red16_dpp(qr);

            const float mean = sr * (1.f / 64.f);
            const float var  = qr * (1.f / 64.f) - mean * mean;
            const float rs   = rsqrtf(var + 1e-6f);
            const float c0   = -mean * rs;

            float4 y;
            y.x = fmaf(fmaf(x.x, rs, c0), gr.x, br.x);
            y.y = fmaf(fmaf(x.y, rs, c0), gr.y, br.y);
            y.z = fmaf(fmaf(x.z, rs, c0), gr.z, br.z);
            y.w = fmaf(fmaf(x.w, rs, c0), gr.w, br.w);
            onr[k * 64 + l] = y;
        }
    }
    {   // ---- imag part ----
        const float4 gi  = ((const float4*)g_i)[q];
        const float4 bi4 = ((const float4*)b_i)[q];
#pragma unroll
        for (int k = 0; k < 4; ++k) {
            ri.x = fmaf(attn[k], m_i[k].x, ri.x); ri.y = fmaf(attn[k], m_i[k].y, ri.y);
            ri.z = fmaf(attn[k], m_i[k].z, ri.z); ri.w = fmaf(attn[k], m_i[k].w, ri.w);

            const int s = h2 * 16 + k * 4 + g;
            const float sp = (s == i1) ? v1 : (s == i2) ? v2 : (s == i3) ? v3 : 0.f;
            const float eu = wgate * sp * inv_ssum;
            const float om = 1.f - eu;

            float4 x;
            x.x = om * m_i[k].x + eu * q4i.x;
            x.y = om * m_i[k].y + eu * q4i.y;
            x.z = om * m_i[k].z + eu * q4i.z;
            x.w = om * m_i[k].w + eu * q4i.w;

            float si = (x.x + x.y) + (x.z + x.w);
            float qi = x.x * x.x; qi = fmaf(x.y, x.y, qi); qi = fmaf(x.z, x.z, qi); qi = fmaf(x.w, x.w, qi);
            si = red16_dpp(si);
            qi = red16_dpp(qi);

            const float mean = si * (1.f / 64.f);
            const float var  = qi * (1.f / 64.f) - mean * mean;
            const float rs   = rsqrtf(var + 1e-6f);
            const float c0   = -mean * rs;

            float4 y;
            y.x = fmaf(fmaf(x.x, rs, c0), gi.x, bi4.x);
            y.y = fmaf(fmaf(x.y, rs, c0), gi.y, bi4.y);
            y.z = fmaf(fmaf(x.z, rs, c0), gi.z, bi4.z);
            y.w = fmaf(fmaf(x.w, rs, c0), gi.w, bi4.w);
            oni[k * 64 + l] = y;
        }
    }

    // ---- read vector: reduce within wave, then across the pair via LDS ----
    rr.x += __shfl_xor(rr.x, 16); rr.y += __shfl_xor(rr.y, 16);
    rr.z += __shfl_xor(rr.z, 16); rr.w += __shfl_xor(rr.w, 16);
    rr.x += __shfl_xor(rr.x, 32); rr.y += __shfl_xor(rr.y, 32);
    rr.z += __shfl_xor(rr.z, 32); rr.w += __shfl_xor(rr.w, 32);
    ri.x += __shfl_xor(ri.x, 16); ri.y += __shfl_xor(ri.y, 16);
    ri.z += __shfl_xor(ri.z, 16); ri.w += __shfl_xor(ri.w, 16);
    ri.x += __shfl_xor(ri.x, 32); ri.y += __shfl_xor(ri.y, 32);
    ri.z += __shfl_xor(ri.z, 32); ri.w += __shfl_xor(ri.w, 32);
    if (g == 0) {
        xchR[wave][q] = rr;
        xchI[wave][q] = ri;
    }
    __syncthreads();
    if (h2 == 0 && g == 0) {
        const float4 pr = xchR[wave ^ 1][q];
        const float4 pi = xchI[wave ^ 1][q];
        float4 or_, oi_;
        or_.x = rr.x + pr.x; or_.y = rr.y + pr.y; or_.z = rr.z + pr.z; or_.w = rr.w + pr.w;
        oi_.x = ri.x + pi.x; oi_.y = ri.y + pi.y; oi_.z = ri.z + pi.z; oi_.w = ri.w + pi.w;
        ((float4*)o_read_r)[b * 16 + q] = or_;
        ((float4*)o_read_i)[b * 16 + q] = oi_;
    }
}

// deterministic fixed-order reduction of the 16384 per-row entropy partials
__global__ __launch_bounds__(1024) void ent_reduce(const float* __restrict__ ws_ent,
                                                   float* __restrict__ o_ent)
{
    __shared__ float red[1024];
    const int t = threadIdx.x;
    float s = 0.f;
    for (int i = t; i < Bn; i += 1024) s += ws_ent[i];
    red[t] = s;
    __syncthreads();
    for (int st = 512; st > 0; st >>= 1) {
        if (t < st) red[t] += red[t + st];
        __syncthreads();
    }
    if (t == 0) o_ent[0] = red[0] * (1.0f / (float)Bn);
}

extern "C" void kernel_launch(void* const* d_in, const int* in_sizes, int n_in,
                              void* d_out, int out_size, void* d_ws, size_t ws_size,
                              hipStream_t stream)
{
    const float* gw_r  = (const float*)d_in[0];
    const float* gw_i  = (const float*)d_in[1];
    const float* mem_r = (const float*)d_in[2];
    const float* mem_i = (const float*)d_in[3];
    const float* Wg    = (const float*)d_in[4];
    const float* bg    = (const float*)d_in[5];
    const float* Wa    = (const float*)d_in[6];
    const float* ba    = (const float*)d_in[7];
    const float* g_r   = (const float*)d_in[8];
    const float* b_r   = (const float*)d_in[9];
    const float* g_i   = (const float*)d_in[10];
    const float* b_i   = (const float*)d_in[11];

    float* out = (float*)d_out;
    const size_t nBD  = (size_t)Bn * Dn;         // 1048576
    const size_t nBSD = (size_t)Bn * Sn * Dn;    // 33554432
    float* o_read_r = out;
    float* o_read_i = out + nBD;
    float* o_next_r = out + 2 * nBD;
    float* o_next_i = out + 2 * nBD + nBSD;
    float* o_ent    = out + 2 * nBD + 2 * nBSD;

    float* ws_ent = (float*)d_ws;   // Bn floats of scratch

    amem_fwd<<<Bn / 2, 256, 0, stream>>>(
        gw_r, gw_i, mem_r, mem_i, Wg, bg, Wa, ba, g_r, b_r, g_i, b_i,
        o_read_r, o_read_i, o_next_r, o_next_i, ws_ent);
    ent_reduce<<<1, 1024, 0, stream>>>(ws_ent, o_ent);
}

// Round 7
// 159.674 us; speedup vs baseline: 1.1110x; 1.1110x over previous
//
#include <hip/hip_runtime.h>
#include <cstddef>

// Problem constants (match reference)
constexpr int Bn = 16384;
constexpr int Sn = 32;
constexpr int Dn = 64;

// ---------- within-16-lane sum via DPP (identical order to xor1/2/4/8 tree) ----
__device__ __forceinline__ float dpp_add(float v, const int ctrl) {
    int t;
    switch (ctrl) {  // ctrl must be a literal constant for the builtin
        case 0xB1:  t = __builtin_amdgcn_update_dpp(0, __builtin_bit_cast(int, v), 0xB1, 0xF, 0xF, true); break;
        case 0x4E:  t = __builtin_amdgcn_update_dpp(0, __builtin_bit_cast(int, v), 0x4E, 0xF, 0xF, true); break;
        case 0x141: t = __builtin_amdgcn_update_dpp(0, __builtin_bit_cast(int, v), 0x141, 0xF, 0xF, true); break;
        default:    t = __builtin_amdgcn_update_dpp(0, __builtin_bit_cast(int, v), 0x140, 0xF, 0xF, true); break;
    }
    return v + __builtin_bit_cast(float, t);
}

__device__ __forceinline__ float red16_dpp(float v) {
    v = dpp_add(v, 0xB1);   // quad_perm [1,0,3,2]  == xor 1
    v = dpp_add(v, 0x4E);   // quad_perm [2,3,0,1]  == xor 2
    v = dpp_add(v, 0x141);  // row_half_mirror      (== xor 4 once quad-uniform)
    v = dpp_add(v, 0x140);  // row_mirror           (== xor 8 once 8-uniform)
    return v;
}

// 8 waves/block, one row per wave. R2 structure (register-resident mem tile,
// fused everything, plain stores) + middle-section reordered for latency hiding.
__global__ __launch_bounds__(512, 4) void amem_fwd(
    const float* __restrict__ gw_r, const float* __restrict__ gw_i,
    const float* __restrict__ mem_r, const float* __restrict__ mem_i,
    const float* __restrict__ Wg,   const float* __restrict__ bg,
    const float* __restrict__ Wa,   const float* __restrict__ ba,
    const float* __restrict__ g_r,  const float* __restrict__ b_r,
    const float* __restrict__ g_i,  const float* __restrict__ b_i,
    float* __restrict__ o_read_r, float* __restrict__ o_read_i,
    float* __restrict__ o_next_r, float* __restrict__ o_next_i,
    float* __restrict__ ws_ent)
{
    __shared__ float sWa[4096];        // Wa staged once per block: [128][32] row-major
    __shared__ float lflat[8][128];    // per-wave [gw_r; gw_i] broadcast

    const int tid  = threadIdx.x;
    const int wave = tid >> 6;     // 8 waves/block, one row each
    const int l    = tid & 63;
    const int b    = blockIdx.x * 8 + wave;
    const int g    = l >> 4;       // slot-group 0..3
    const int q    = l & 15;       // d0 = q*4

    const float4 q4r = ((const float4*)gw_r)[b * 16 + q];
    const float4 q4i = ((const float4*)gw_i)[b * 16 + q];

    // ---- issue this row's mem loads FIRST (the only HBM read of it) ----
    // lane l, iter k holds float4 at (s = k*4 + g, d = q*4 .. q*4+3)
    const float4* mr4 = (const float4*)mem_r + (size_t)b * 512;
    const float4* mi4 = (const float4*)mem_i + (size_t)b * 512;
    float4 m_r[8], m_i[8];
#pragma unroll
    for (int k = 0; k < 8; ++k) {
        m_r[k] = mr4[k * 64 + l];
        m_i[k] = mi4[k * 64 + l];
    }

    // ---- stage Wa into LDS (block-wide, once) + flat broadcast ----
    {
        const float4* Wa4 = (const float4*)Wa;
        float4* sWa4 = (float4*)sWa;
        sWa4[tid]       = Wa4[tid];
        sWa4[tid + 512] = Wa4[tid + 512];
    }
    if (g == 0)      *(float4*)&lflat[wave][q * 4]      = q4r;
    else if (g == 1) *(float4*)&lflat[wave][64 + q * 4] = q4i;
    __syncthreads();

    // ================= middle section (gw-only; hides mem-load latency) =====
    // ---- write gate: sigmoid([gw_r;gw_i] @ Wg + bg) ----
    const float4 wg0 = ((const float4*)Wg)[q];
    const float4 wg1 = ((const float4*)Wg)[16 + q];
    float wp = q4r.x * wg0.x + q4r.y * wg0.y + q4r.z * wg0.z + q4r.w * wg0.w
             + q4i.x * wg1.x + q4i.y * wg1.y + q4i.z * wg1.z + q4i.w * wg1.w;
    wp = red16_dpp(wp);
    const float wgate = 1.0f / (1.0f + __expf(-(wp + bg[0])));

    // ---- logits = [gw_r;gw_i] @ Wa + ba (Wa from LDS, 4 independent accs) ----
    const int sl = l & 31;   // slot this lane owns (duplicated across halves)
    const int h  = l >> 5;
    const float* WaL = sWa + h * 2048;                  // h*64 rows of 32
    const float4* lf4 = (const float4*)&lflat[wave][h * 64];
    float a0 = 0.f, a1 = 0.f, a2 = 0.f, a3 = 0.f;
#pragma unroll
    for (int jj = 0; jj < 16; ++jj) {
        const float4 f = lf4[jj];
        const int r0 = jj * 4;
        a0 = fmaf(f.x, WaL[(r0 + 0) * 32 + sl], a0);
        a1 = fmaf(f.y, WaL[(r0 + 1) * 32 + sl], a1);
        a2 = fmaf(f.z, WaL[(r0 + 2) * 32 + sl], a2);
        a3 = fmaf(f.w, WaL[(r0 + 3) * 32 + sl], a3);
    }
    float acc = (a0 + a1) + (a2 + a3);
    acc += __shfl_xor(acc, 32);   // combine real/imag halves
    acc += ba[sl];

    // softmax over 32 slots (within each 32-lane half; halves identical)
    float lm = acc;
    lm = fmaxf(lm, __shfl_xor(lm, 1));
    lm = fmaxf(lm, __shfl_xor(lm, 2));
    lm = fmaxf(lm, __shfl_xor(lm, 4));
    lm = fmaxf(lm, __shfl_xor(lm, 8));
    lm = fmaxf(lm, __shfl_xor(lm, 16));
    const float we = __expf(acc - lm);
    float wsum = we;
    wsum += __shfl_xor(wsum, 1);
    wsum += __shfl_xor(wsum, 2);
    wsum += __shfl_xor(wsum, 4);
    wsum += __shfl_xor(wsum, 8);
    wsum += __shfl_xor(wsum, 16);
    const float ww = we / wsum;

    // entropy partial (deterministic: per-row partial, reduced by kernel 2)
    float et = ww * __logf(ww + 1e-10f);
    et += __shfl_xor(et, 1);
    et += __shfl_xor(et, 2);
    et += __shfl_xor(et, 4);
    et += __shfl_xor(et, 8);
    et += __shfl_xor(et, 16);
    if (l == 0) ws_ent[b] = -et;

    // ---- top-3 via 3 argmax butterflies (value desc, index asc on ties) ----
    float lv = ww;   // live value; knocked out after selection (ww >= 0 so -1 works)
    float v1, v2, v3;
    int   i1, i2, i3;
#pragma unroll
    for (int pass = 0; pass < 3; ++pass) {
        float bv = lv;
        int   bi = sl;
#pragma unroll
        for (int d = 1; d <= 16; d <<= 1) {
            const float ov = __shfl_xor(bv, d);
            const int   oi = __shfl_xor(bi, d);
            if (ov > bv || (ov == bv && oi < bi)) { bv = ov; bi = oi; }
        }
        if (pass == 0) { v1 = bv; i1 = bi; }
        else if (pass == 1) { v2 = bv; i2 = bi; }
        else { v3 = bv; i3 = bi; }
        if (sl == bi) lv = -1.f;
    }
    const float inv_ssum = 1.0f / (v1 + v2 + v3 + 1e-6f);

    // ================= sim + slot softmax (first consumption of m_r/m_i) ====
    float sims[8];
#pragma unroll
    for (int k = 0; k < 8; ++k) {
        float p = m_r[k].x * q4r.x + m_r[k].y * q4r.y + m_r[k].z * q4r.z + m_r[k].w * q4r.w
                + m_i[k].x * q4i.x + m_i[k].y * q4i.y + m_i[k].z * q4i.z + m_i[k].w * q4i.w;
        sims[k] = red16_dpp(p);
    }
    float mx = sims[0];
#pragma unroll
    for (int k = 1; k < 8; ++k) mx = fmaxf(mx, sims[k]);
    mx = fmaxf(mx, __shfl_xor(mx, 16));
    mx = fmaxf(mx, __shfl_xor(mx, 32));
    float attn[8];
    float asum = 0.f;
#pragma unroll
    for (int k = 0; k < 8; ++k) { attn[k] = __expf(sims[k] - mx); asum += attn[k]; }
    asum += __shfl_xor(asum, 16);
    asum += __shfl_xor(asum, 32);
    const float ainv = 1.0f / asum;
#pragma unroll
    for (int k = 0; k < 8; ++k) attn[k] *= ainv;

    // ---- fused: read accumulation + blend + dual LayerNorm + plain stores ----
    const float4 gr  = ((const float4*)g_r)[q];
    const float4 br  = ((const float4*)b_r)[q];
    const float4 gi  = ((const float4*)g_i)[q];
    const float4 bi4 = ((const float4*)b_i)[q];
    float4* onr = (float4*)o_next_r + (size_t)b * 512;
    float4* oni = (float4*)o_next_i + (size_t)b * 512;
    float4 rr = {0.f, 0.f, 0.f, 0.f}, ri = {0.f, 0.f, 0.f, 0.f};

#pragma unroll
    for (int k = 0; k < 8; ++k) {
        rr.x = fmaf(attn[k], m_r[k].x, rr.x); rr.y = fmaf(attn[k], m_r[k].y, rr.y);
        rr.z = fmaf(attn[k], m_r[k].z, rr.z); rr.w = fmaf(attn[k], m_r[k].w, rr.w);
        ri.x = fmaf(attn[k], m_i[k].x, ri.x); ri.y = fmaf(attn[k], m_i[k].y, ri.y);
        ri.z = fmaf(attn[k], m_i[k].z, ri.z); ri.w = fmaf(attn[k], m_i[k].w, ri.w);

        const int s = k * 4 + g;
        const float sp = (s == i1) ? v1 : (s == i2) ? v2 : (s == i3) ? v3 : 0.f;
        const float eu = wgate * sp * inv_ssum;
        const float om = 1.f - eu;

        float4 xr, xi;
        xr.x = om * m_r[k].x + eu * q4r.x;
        xr.y = om * m_r[k].y + eu * q4r.y;
        xr.z = om * m_r[k].z + eu * q4r.z;
        xr.w = om * m_r[k].w + eu * q4r.w;
        xi.x = om * m_i[k].x + eu * q4i.x;
        xi.y = om * m_i[k].y + eu * q4i.y;
        xi.z = om * m_i[k].z + eu * q4i.z;
        xi.w = om * m_i[k].w + eu * q4i.w;

        float sr = (xr.x + xr.y) + (xr.z + xr.w);
        float si = (xi.x + xi.y) + (xi.z + xi.w);
        float qr = xr.x * xr.x; qr = fmaf(xr.y, xr.y, qr); qr = fmaf(xr.z, xr.z, qr); qr = fmaf(xr.w, xr.w, qr);
        float qi = xi.x * xi.x; qi = fmaf(xi.y, xi.y, qi); qi = fmaf(xi.z, xi.z, qi); qi = fmaf(xi.w, xi.w, qi);

        // within-16 reductions entirely on the VALU (no LDS traffic)
        sr = red16_dpp(sr);
        si = red16_dpp(si);
        qr = red16_dpp(qr);
        qi = red16_dpp(qi);

        const float mr_ = sr * (1.f / 64.f);
        const float mi_ = si * (1.f / 64.f);
        const float vr  = qr * (1.f / 64.f) - mr_ * mr_;
        const float vi  = qi * (1.f / 64.f) - mi_ * mi_;
        const float ar  = rsqrtf(vr + 1e-6f);
        const float ai  = rsqrtf(vi + 1e-6f);
        const float cr  = -mr_ * ar;
        const float ci  = -mi_ * ai;

        float4 yr, yi;
        yr.x = fmaf(fmaf(xr.x, ar, cr), gr.x, br.x);
        yr.y = fmaf(fmaf(xr.y, ar, cr), gr.y, br.y);
        yr.z = fmaf(fmaf(xr.z, ar, cr), gr.z, br.z);
        yr.w = fmaf(fmaf(xr.w, ar, cr), gr.w, br.w);
        yi.x = fmaf(fmaf(xi.x, ai, ci), gi.x, bi4.x);
        yi.y = fmaf(fmaf(xi.y, ai, ci), gi.y, bi4.y);
        yi.z = fmaf(fmaf(xi.z, ai, ci), gi.z, bi4.z);
        yi.w = fmaf(fmaf(xi.w, ai, ci), gi.w, bi4.w);
        onr[k * 64 + l] = yr;
        oni[k * 64 + l] = yi;
    }

    // read output: reduce across the 4 slot-groups
    rr.x += __shfl_xor(rr.x, 16); rr.y += __shfl_xor(rr.y, 16);
    rr.z += __shfl_xor(rr.z, 16); rr.w += __shfl_xor(rr.w, 16);
    rr.x += __shfl_xor(rr.x, 32); rr.y += __shfl_xor(rr.y, 32);
    rr.z += __shfl_xor(rr.z, 32); rr.w += __shfl_xor(rr.w, 32);
    ri.x += __shfl_xor(ri.x, 16); ri.y += __shfl_xor(ri.y, 16);
    ri.z += __shfl_xor(ri.z, 16); ri.w += __shfl_xor(ri.w, 16);
    ri.x += __shfl_xor(ri.x, 32); ri.y += __shfl_xor(ri.y, 32);
    ri.z += __shfl_xor(ri.z, 32); ri.w += __shfl_xor(ri.w, 32);
    if (g == 0) {
        ((float4*)o_read_r)[b * 16 + q] = rr;
        ((float4*)o_read_i)[b * 16 + q] = ri;
    }
}

// deterministic fixed-order reduction of the 16384 per-row entropy partials
__global__ __launch_bounds__(1024) void ent_reduce(const float* __restrict__ ws_ent,
                                                   float* __restrict__ o_ent)
{
    __shared__ float red[1024];
    const int t = threadIdx.x;
    float s = 0.f;
    for (int i = t; i < Bn; i += 1024) s += ws_ent[i];
    red[t] = s;
    __syncthreads();
    for (int st = 512; st > 0; st >>= 1) {
        if (t < st) red[t] += red[t + st];
        __syncthreads();
    }
    if (t == 0) o_ent[0] = red[0] * (1.0f / (float)Bn);
}

extern "C" void kernel_launch(void* const* d_in, const int* in_sizes, int n_in,
                              void* d_out, int out_size, void* d_ws, size_t ws_size,
                              hipStream_t stream)
{
    const float* gw_r  = (const float*)d_in[0];
    const float* gw_i  = (const float*)d_in[1];
    const float* mem_r = (const float*)d_in[2];
    const float* mem_i = (const float*)d_in[3];
    const float* Wg    = (const float*)d_in[4];
    const float* bg    = (const float*)d_in[5];
    const float* Wa    = (const float*)d_in[6];
    const float* ba    = (const float*)d_in[7];
    const float* g_r   = (const float*)d_in[8];
    const float* b_r   = (const float*)d_in[9];
    const float* g_i   = (const float*)d_in[10];
    const float* b_i   = (const float*)d_in[11];

    float* out = (float*)d_out;
    const size_t nBD  = (size_t)Bn * Dn;         // 1048576
    const size_t nBSD = (size_t)Bn * Sn * Dn;    // 33554432
    float* o_read_r = out;
    float* o_read_i = out + nBD;
    float* o_next_r = out + 2 * nBD;
    float* o_next_i = out + 2 * nBD + nBSD;
    float* o_ent    = out + 2 * nBD + 2 * nBSD;

    float* ws_ent = (float*)d_ws;   // Bn floats of scratch

    amem_fwd<<<Bn / 8, 512, 0, stream>>>(
        gw_r, gw_i, mem_r, mem_i, Wg, bg, Wa, ba, g_r, b_r, g_i, b_i,
        o_read_r, o_read_i, o_next_r, o_next_i, ws_ent);
    ent_reduce<<<1, 1024, 0, stream>>>(ws_ent, o_ent);
}

// Round 8
// 118.710 us; speedup vs baseline: 1.4944x; 1.3451x over previous
//
#include <hip/hip_runtime.h>
#include <cstddef>

// Problem constants (match reference)
constexpr int Bn = 16384;
constexpr int Sn = 32;
constexpr int Dn = 64;

// ---------- DPP helpers: within-16-lane exchange on the VALU ----------
// ctrl 0xB1 = quad_perm [1,0,3,2] (== xor 1)
// ctrl 0x4E = quad_perm [2,3,0,1] (== xor 2)
// ctrl 0x141 = row_half_mirror    (== xor 4 once quad-uniform)
// ctrl 0x140 = row_mirror         (== xor 8 once 8-uniform)
template <int CTRL>
__device__ __forceinline__ float dpp_movf(float v) {
    return __builtin_bit_cast(float,
        __builtin_amdgcn_update_dpp(0, __builtin_bit_cast(int, v), CTRL, 0xF, 0xF, true));
}
template <int CTRL>
__device__ __forceinline__ int dpp_movi(int v) {
    return __builtin_amdgcn_update_dpp(0, v, CTRL, 0xF, 0xF, true);
}

__device__ __forceinline__ float red16_dpp(float v) {
    v += dpp_movf<0xB1>(v);
    v += dpp_movf<0x4E>(v);
    v += dpp_movf<0x141>(v);
    v += dpp_movf<0x140>(v);
    return v;
}
// 32-wide sum: DPP for stages 1/2/4/8, shuffle for 16 (crosses DPP row)
__device__ __forceinline__ float red32_add(float v) {
    v = red16_dpp(v);
    v += __shfl_xor(v, 16);
    return v;
}
__device__ __forceinline__ float red32_max(float v) {
    v = fmaxf(v, dpp_movf<0xB1>(v));
    v = fmaxf(v, dpp_movf<0x4E>(v));
    v = fmaxf(v, dpp_movf<0x141>(v));
    v = fmaxf(v, dpp_movf<0x140>(v));
    v = fmaxf(v, __shfl_xor(v, 16));
    return v;
}

// one argmax butterfly stage: exchange (bv,bi), keep (max, lowest idx on tie)
#define ARGMAX_DPP_STAGE(CTRL)                                        \
    {                                                                 \
        const float ov = dpp_movf<CTRL>(bv);                          \
        const int   oi = dpp_movi<CTRL>(bi);                          \
        if (ov > bv || (ov == bv && oi < bi)) { bv = ov; bi = oi; }   \
    }

// R2 structure exactly: 4 waves/block, one row per wave, register-resident
// mem tile, fused everything, plain stores. Only reductions switched to DPP.
__global__ __launch_bounds__(256, 4) void amem_fwd(
    const float* __restrict__ gw_r, const float* __restrict__ gw_i,
    const float* __restrict__ mem_r, const float* __restrict__ mem_i,
    const float* __restrict__ Wg,   const float* __restrict__ bg,
    const float* __restrict__ Wa,   const float* __restrict__ ba,
    const float* __restrict__ g_r,  const float* __restrict__ b_r,
    const float* __restrict__ g_i,  const float* __restrict__ b_i,
    float* __restrict__ o_read_r, float* __restrict__ o_read_i,
    float* __restrict__ o_next_r, float* __restrict__ o_next_i,
    float* __restrict__ ws_ent)
{
    __shared__ float sWa[4096];        // Wa staged once per block: [128][32] row-major
    __shared__ float lflat[4][128];    // per-wave [gw_r; gw_i] broadcast

    const int tid  = threadIdx.x;
    const int wave = tid >> 6;     // 4 waves/block, one row each
    const int l    = tid & 63;
    const int b    = blockIdx.x * 4 + wave;
    const int g    = l >> 4;       // slot-group 0..3
    const int q    = l & 15;       // d0 = q*4

    // ---- load this row's memory into registers (the only HBM read of it) ----
    // lane l, iter k holds float4 at (s = k*4 + g, d = q*4 .. q*4+3)
    const float4* mr4 = (const float4*)mem_r + (size_t)b * 512;
    const float4* mi4 = (const float4*)mem_i + (size_t)b * 512;
    float4 m_r[8], m_i[8];
#pragma unroll
    for (int k = 0; k < 8; ++k) {
        m_r[k] = mr4[k * 64 + l];
        m_i[k] = mi4[k * 64 + l];
    }
    const float4 q4r = ((const float4*)gw_r)[b * 16 + q];
    const float4 q4i = ((const float4*)gw_i)[b * 16 + q];

    // ---- stage Wa into LDS (block-wide, once) + flat broadcast ----
    {
        const float4* Wa4 = (const float4*)Wa;
        float4* sWa4 = (float4*)sWa;
#pragma unroll
        for (int j = 0; j < 4; ++j) sWa4[tid + 256 * j] = Wa4[tid + 256 * j];
    }
    if (g == 0)      *(float4*)&lflat[wave][q * 4]      = q4r;
    else if (g == 1) *(float4*)&lflat[wave][64 + q * 4] = q4i;
    __syncthreads();

    // ---- sim[s] = <mem_r[s,:], gw_r> + <mem_i[s,:], gw_i> ----
    float sims[8];
#pragma unroll
    for (int k = 0; k < 8; ++k) {
        float p = m_r[k].x * q4r.x + m_r[k].y * q4r.y + m_r[k].z * q4r.z + m_r[k].w * q4r.w
                + m_i[k].x * q4i.x + m_i[k].y * q4i.y + m_i[k].z * q4i.z + m_i[k].w * q4i.w;
        sims[k] = red16_dpp(p);   // sum over d within the 16-lane group
    }
    // softmax over all 32 slots (8 per lane across k, x4 groups)
    float mx = sims[0];
#pragma unroll
    for (int k = 1; k < 8; ++k) mx = fmaxf(mx, sims[k]);
    mx = fmaxf(mx, __shfl_xor(mx, 16));
    mx = fmaxf(mx, __shfl_xor(mx, 32));
    float attn[8];
    float asum = 0.f;
#pragma unroll
    for (int k = 0; k < 8; ++k) { attn[k] = __expf(sims[k] - mx); asum += attn[k]; }
    asum += __shfl_xor(asum, 16);
    asum += __shfl_xor(asum, 32);
    const float ainv = 1.0f / asum;

    // ---- read = attn @ mem ----
    float4 rr = {0.f, 0.f, 0.f, 0.f}, ri = {0.f, 0.f, 0.f, 0.f};
#pragma unroll
    for (int k = 0; k < 8; ++k) {
        const float a = attn[k] * ainv;
        rr.x = fmaf(a, m_r[k].x, rr.x); rr.y = fmaf(a, m_r[k].y, rr.y);
        rr.z = fmaf(a, m_r[k].z, rr.z); rr.w = fmaf(a, m_r[k].w, rr.w);
        ri.x = fmaf(a, m_i[k].x, ri.x); ri.y = fmaf(a, m_i[k].y, ri.y);
        ri.z = fmaf(a, m_i[k].z, ri.z); ri.w = fmaf(a, m_i[k].w, ri.w);
    }
    rr.x += __shfl_xor(rr.x, 16); rr.y += __shfl_xor(rr.y, 16);
    rr.z += __shfl_xor(rr.z, 16); rr.w += __shfl_xor(rr.w, 16);
    rr.x += __shfl_xor(rr.x, 32); rr.y += __shfl_xor(rr.y, 32);
    rr.z += __shfl_xor(rr.z, 32); rr.w += __shfl_xor(rr.w, 32);
    ri.x += __shfl_xor(ri.x, 16); ri.y += __shfl_xor(ri.y, 16);
    ri.z += __shfl_xor(ri.z, 16); ri.w += __shfl_xor(ri.w, 16);
    ri.x += __shfl_xor(ri.x, 32); ri.y += __shfl_xor(ri.y, 32);
    ri.z += __shfl_xor(ri.z, 32); ri.w += __shfl_xor(ri.w, 32);
    if (g == 0) {
        ((float4*)o_read_r)[b * 16 + q] = rr;
        ((float4*)o_read_i)[b * 16 + q] = ri;
    }

    // ---- write gate: sigmoid([gw_r;gw_i] @ Wg + bg) ----
    const float4 wg0 = ((const float4*)Wg)[q];
    const float4 wg1 = ((const float4*)Wg)[16 + q];
    float wp = q4r.x * wg0.x + q4r.y * wg0.y + q4r.z * wg0.z + q4r.w * wg0.w
             + q4i.x * wg1.x + q4i.y * wg1.y + q4i.z * wg1.z + q4i.w * wg1.w;
    wp = red16_dpp(wp);
    const float wgate = 1.0f / (1.0f + __expf(-(wp + bg[0])));

    // ---- logits = [gw_r;gw_i] @ Wa + ba (Wa from LDS, 4 independent accs) ----
    const int sl = l & 31;   // slot this lane owns (duplicated across halves)
    const int h  = l >> 5;
    const float* WaL = sWa + h * 2048;                  // h*64 rows of 32
    const float4* lf4 = (const float4*)&lflat[wave][h * 64];
    float a0 = 0.f, a1 = 0.f, a2 = 0.f, a3 = 0.f;
#pragma unroll
    for (int jj = 0; jj < 16; ++jj) {
        const float4 f = lf4[jj];
        const int r0 = jj * 4;
        a0 = fmaf(f.x, WaL[(r0 + 0) * 32 + sl], a0);
        a1 = fmaf(f.y, WaL[(r0 + 1) * 32 + sl], a1);
        a2 = fmaf(f.z, WaL[(r0 + 2) * 32 + sl], a2);
        a3 = fmaf(f.w, WaL[(r0 + 3) * 32 + sl], a3);
    }
    float acc = (a0 + a1) + (a2 + a3);
    acc += __shfl_xor(acc, 32);   // combine real/imag halves
    acc += ba[sl];

    // softmax over 32 slots (within each 32-lane half; halves identical)
    const float lm = red32_max(acc);
    const float we = __expf(acc - lm);
    const float wsum = red32_add(we);
    const float ww = we / wsum;

    // entropy partial (deterministic: per-row partial, reduced by kernel 2)
    const float et = red32_add(ww * __logf(ww + 1e-10f));
    if (l == 0) ws_ent[b] = -et;

    // ---- top-3 via 3 argmax butterflies (value desc, index asc on ties) ----
    float lv = ww;   // live value; knocked out after selection (ww >= 0 so -1 works)
    float v1, v2, v3;
    int   i1, i2, i3;
#pragma unroll
    for (int pass = 0; pass < 3; ++pass) {
        float bv = lv;
        int   bi = sl;
        ARGMAX_DPP_STAGE(0xB1);
        ARGMAX_DPP_STAGE(0x4E);
        ARGMAX_DPP_STAGE(0x141);
        ARGMAX_DPP_STAGE(0x140);
        {
            const float ov = __shfl_xor(bv, 16);
            const int   oi = __shfl_xor(bi, 16);
            if (ov > bv || (ov == bv && oi < bi)) { bv = ov; bi = oi; }
        }
        if (pass == 0) { v1 = bv; i1 = bi; }
        else if (pass == 1) { v2 = bv; i2 = bi; }
        else { v3 = bv; i3 = bi; }
        if (sl == bi) lv = -1.f;
    }
    const float inv_ssum = 1.0f / (v1 + v2 + v3 + 1e-6f);

    // ---- blended write + dual LayerNorm (single pass sum/sumsq) + store ----
    const float4 gr  = ((const float4*)g_r)[q];
    const float4 br  = ((const float4*)b_r)[q];
    const float4 gi  = ((const float4*)g_i)[q];
    const float4 bi4 = ((const float4*)b_i)[q];
    float4* onr = (float4*)o_next_r + (size_t)b * 512;
    float4* oni = (float4*)o_next_i + (size_t)b * 512;

#pragma unroll
    for (int k = 0; k < 8; ++k) {
        const int s = k * 4 + g;
        const float sp = (s == i1) ? v1 : (s == i2) ? v2 : (s == i3) ? v3 : 0.f;
        const float eu = wgate * sp * inv_ssum;
        const float om = 1.f - eu;

        float4 xr, xi;
        xr.x = om * m_r[k].x + eu * q4r.x;
        xr.y = om * m_r[k].y + eu * q4r.y;
        xr.z = om * m_r[k].z + eu * q4r.z;
        xr.w = om * m_r[k].w + eu * q4r.w;
        xi.x = om * m_i[k].x + eu * q4i.x;
        xi.y = om * m_i[k].y + eu * q4i.y;
        xi.z = om * m_i[k].z + eu * q4i.z;
        xi.w = om * m_i[k].w + eu * q4i.w;

        float sr = (xr.x + xr.y) + (xr.z + xr.w);
        float si = (xi.x + xi.y) + (xi.z + xi.w);
        float qr = xr.x * xr.x; qr = fmaf(xr.y, xr.y, qr); qr = fmaf(xr.z, xr.z, qr); qr = fmaf(xr.w, xr.w, qr);
        float qi = xi.x * xi.x; qi = fmaf(xi.y, xi.y, qi); qi = fmaf(xi.z, xi.z, qi); qi = fmaf(xi.w, xi.w, qi);

        // within-16 reductions entirely on the VALU (no LDS traffic)
        sr = red16_dpp(sr);
        si = red16_dpp(si);
        qr = red16_dpp(qr);
        qi = red16_dpp(qi);

        const float mr_ = sr * (1.f / 64.f);
        const float mi_ = si * (1.f / 64.f);
        const float vr  = qr * (1.f / 64.f) - mr_ * mr_;
        const float vi  = qi * (1.f / 64.f) - mi_ * mi_;
        const float ar  = rsqrtf(vr + 1e-6f);
        const float ai  = rsqrtf(vi + 1e-6f);
        const float cr  = -mr_ * ar;
        const float ci  = -mi_ * ai;

        float4 yr, yi;
        yr.x = fmaf(fmaf(xr.x, ar, cr), gr.x, br.x);
        yr.y = fmaf(fmaf(xr.y, ar, cr), gr.y, br.y);
        yr.z = fmaf(fmaf(xr.z, ar, cr), gr.z, br.z);
        yr.w = fmaf(fmaf(xr.w, ar, cr), gr.w, br.w);
        yi.x = fmaf(fmaf(xi.x, ai, ci), gi.x, bi4.x);
        yi.y = fmaf(fmaf(xi.y, ai, ci), gi.y, bi4.y);
        yi.z = fmaf(fmaf(xi.z, ai, ci), gi.z, bi4.z);
        yi.w = fmaf(fmaf(xi.w, ai, ci), gi.w, bi4.w);
        onr[k * 64 + l] = yr;
        oni[k * 64 + l] = yi;
    }
}

// deterministic fixed-order reduction of the 16384 per-row entropy partials
__global__ __launch_bounds__(1024) void ent_reduce(const float* __restrict__ ws_ent,
                                                   float* __restrict__ o_ent)
{
    __shared__ float red[1024];
    const int t = threadIdx.x;
    float s = 0.f;
    for (int i = t; i < Bn; i += 1024) s += ws_ent[i];
    red[t] = s;
    __syncthreads();
    for (int st = 512; st > 0; st >>= 1) {
        if (t < st) red[t] += red[t + st];
        __syncthreads();
    }
    if (t == 0) o_ent[0] = red[0] * (1.0f / (float)Bn);
}

extern "C" void kernel_launch(void* const* d_in, const int* in_sizes, int n_in,
                              void* d_out, int out_size, void* d_ws, size_t ws_size,
                              hipStream_t stream)
{
    const float* gw_r  = (const float*)d_in[0];
    const float* gw_i  = (const float*)d_in[1];
    const float* mem_r = (const float*)d_in[2];
    const float* mem_i = (const float*)d_in[3];
    const float* Wg    = (const float*)d_in[4];
    const float* bg    = (const float*)d_in[5];
    const float* Wa    = (const float*)d_in[6];
    const float* ba    = (const float*)d_in[7];
    const float* g_r   = (const float*)d_in[8];
    const float* b_r   = (const float*)d_in[9];
    const float* g_i   = (const float*)d_in[10];
    const float* b_i   = (const float*)d_in[11];

    float* out = (float*)d_out;
    const size_t nBD  = (size_t)Bn * Dn;         // 1048576
    const size_t nBSD = (size_t)Bn * Sn * Dn;    // 33554432
    float* o_read_r = out;
    float* o_read_i = out + nBD;
    float* o_next_r = out + 2 * nBD;
    float* o_next_i = out + 2 * nBD + nBSD;
    float* o_ent    = out + 2 * nBD + 2 * nBSD;

    float* ws_ent = (float*)d_ws;   // Bn floats of scratch

    amem_fwd<<<Bn / 4, 256, 0, stream>>>(
        gw_r, gw_i, mem_r, mem_i, Wg, bg, Wa, ba, g_r, b_r, g_i, b_i,
        o_read_r, o_read_i, o_next_r, o_next_i, ws_ent);
    ent_reduce<<<1, 1024, 0, stream>>>(ws_ent, o_ent);
}

// Round 9
// 116.648 us; speedup vs baseline: 1.5208x; 1.0177x over previous
//
#include <hip/hip_runtime.h>
#include <cstddef>

// Problem constants (match reference)
constexpr int Bn = 16384;
constexpr int Sn = 32;
constexpr int Dn = 64;

// ---------- DPP helpers: within-16-lane exchange on the VALU ----------
// ctrl 0xB1 = quad_perm [1,0,3,2] (== xor 1)
// ctrl 0x4E = quad_perm [2,3,0,1] (== xor 2)
// ctrl 0x141 = row_half_mirror    (== xor 4 once quad-uniform)
// ctrl 0x140 = row_mirror         (== xor 8 once 8-uniform)
template <int CTRL>
__device__ __forceinline__ float dpp_movf(float v) {
    return __builtin_bit_cast(float,
        __builtin_amdgcn_update_dpp(0, __builtin_bit_cast(int, v), CTRL, 0xF, 0xF, true));
}
template <int CTRL>
__device__ __forceinline__ int dpp_movi(int v) {
    return __builtin_amdgcn_update_dpp(0, v, CTRL, 0xF, 0xF, true);
}

__device__ __forceinline__ float red16_dpp(float v) {
    v += dpp_movf<0xB1>(v);
    v += dpp_movf<0x4E>(v);
    v += dpp_movf<0x141>(v);
    v += dpp_movf<0x140>(v);
    return v;
}
// 32-wide sum: DPP for stages 1/2/4/8, shuffle for 16 (crosses DPP row)
__device__ __forceinline__ float red32_add(float v) {
    v = red16_dpp(v);
    v += __shfl_xor(v, 16);
    return v;
}
__device__ __forceinline__ float red32_max(float v) {
    v = fmaxf(v, dpp_movf<0xB1>(v));
    v = fmaxf(v, dpp_movf<0x4E>(v));
    v = fmaxf(v, dpp_movf<0x141>(v));
    v = fmaxf(v, dpp_movf<0x140>(v));
    v = fmaxf(v, __shfl_xor(v, 16));
    return v;
}

// one argmax butterfly stage: exchange (bv,bi), keep (max, lowest idx on tie)
#define ARGMAX_DPP_STAGE(CTRL)                                        \
    {                                                                 \
        const float ov = dpp_movf<CTRL>(bv);                          \
        const int   oi = dpp_movi<CTRL>(bi);                          \
        if (ov > bv || (ov == bv && oi < bi)) { bv = ov; bi = oi; }   \
    }

// R8 structure, with the mem-load issue window moved AFTER the barrier so the
// 32 in-flight loads overlap the gw-only middle section (gate/logits/top-3)
// instead of being drained by __syncthreads' implicit vmcnt(0).
__global__ __launch_bounds__(256, 4) void amem_fwd(
    const float* __restrict__ gw_r, const float* __restrict__ gw_i,
    const float* __restrict__ mem_r, const float* __restrict__ mem_i,
    const float* __restrict__ Wg,   const float* __restrict__ bg,
    const float* __restrict__ Wa,   const float* __restrict__ ba,
    const float* __restrict__ g_r,  const float* __restrict__ b_r,
    const float* __restrict__ g_i,  const float* __restrict__ b_i,
    float* __restrict__ o_read_r, float* __restrict__ o_read_i,
    float* __restrict__ o_next_r, float* __restrict__ o_next_i,
    float* __restrict__ ws_ent)
{
    __shared__ float sWa[4096];        // Wa staged once per block: [128][32] row-major
    __shared__ float lflat[4][128];    // per-wave [gw_r; gw_i] broadcast

    const int tid  = threadIdx.x;
    const int wave = tid >> 6;     // 4 waves/block, one row each
    const int l    = tid & 63;
    const int b    = blockIdx.x * 4 + wave;
    const int g    = l >> 4;       // slot-group 0..3
    const int q    = l & 15;       // d0 = q*4

    const float4 q4r = ((const float4*)gw_r)[b * 16 + q];
    const float4 q4i = ((const float4*)gw_i)[b * 16 + q];

    // ---- stage Wa into LDS (block-wide, once) + flat broadcast, THEN barrier.
    // Nothing else is in flight, so the barrier's implicit vmcnt(0) is free.
    {
        const float4* Wa4 = (const float4*)Wa;
        float4* sWa4 = (float4*)sWa;
#pragma unroll
        for (int j = 0; j < 4; ++j) sWa4[tid + 256 * j] = Wa4[tid + 256 * j];
    }
    if (g == 0)      *(float4*)&lflat[wave][q * 4]      = q4r;
    else if (g == 1) *(float4*)&lflat[wave][64 + q * 4] = q4i;
    __syncthreads();

    // ---- issue this row's mem loads NOW; the middle section below runs with
    // them in flight (no vmcnt waits until sim).
    const float4* mr4 = (const float4*)mem_r + (size_t)b * 512;
    const float4* mi4 = (const float4*)mem_i + (size_t)b * 512;
    float4 m_r[8], m_i[8];
#pragma unroll
    for (int k = 0; k < 8; ++k) {
        m_r[k] = mr4[k * 64 + l];
        m_i[k] = mi4[k * 64 + l];
    }

    // ================= middle section (gw-only; hides mem-load latency) =====
    // ---- write gate: sigmoid([gw_r;gw_i] @ Wg + bg) ----
    const float4 wg0 = ((const float4*)Wg)[q];
    const float4 wg1 = ((const float4*)Wg)[16 + q];
    float wp = q4r.x * wg0.x + q4r.y * wg0.y + q4r.z * wg0.z + q4r.w * wg0.w
             + q4i.x * wg1.x + q4i.y * wg1.y + q4i.z * wg1.z + q4i.w * wg1.w;
    wp = red16_dpp(wp);
    const float wgate = 1.0f / (1.0f + __expf(-(wp + bg[0])));

    // ---- logits = [gw_r;gw_i] @ Wa + ba (Wa from LDS, 4 independent accs) ----
    const int sl = l & 31;   // slot this lane owns (duplicated across halves)
    const int h  = l >> 5;
    const float* WaL = sWa + h * 2048;                  // h*64 rows of 32
    const float4* lf4 = (const float4*)&lflat[wave][h * 64];
    float a0 = 0.f, a1 = 0.f, a2 = 0.f, a3 = 0.f;
#pragma unroll
    for (int jj = 0; jj < 16; ++jj) {
        const float4 f = lf4[jj];
        const int r0 = jj * 4;
        a0 = fmaf(f.x, WaL[(r0 + 0) * 32 + sl], a0);
        a1 = fmaf(f.y, WaL[(r0 + 1) * 32 + sl], a1);
        a2 = fmaf(f.z, WaL[(r0 + 2) * 32 + sl], a2);
        a3 = fmaf(f.w, WaL[(r0 + 3) * 32 + sl], a3);
    }
    float acc = (a0 + a1) + (a2 + a3);
    acc += __shfl_xor(acc, 32);   // combine real/imag halves
    acc += ba[sl];

    // softmax over 32 slots (within each 32-lane half; halves identical)
    const float lm = red32_max(acc);
    const float we = __expf(acc - lm);
    const float wsum = red32_add(we);
    const float ww = we / wsum;

    // entropy partial (deterministic: per-row partial, reduced by kernel 2)
    const float et = red32_add(ww * __logf(ww + 1e-10f));
    if (l == 0) ws_ent[b] = -et;

    // ---- top-3 via 3 argmax butterflies (value desc, index asc on ties) ----
    float lv = ww;   // live value; knocked out after selection (ww >= 0 so -1 works)
    float v1, v2, v3;
    int   i1, i2, i3;
#pragma unroll
    for (int pass = 0; pass < 3; ++pass) {
        float bv = lv;
        int   bi = sl;
        ARGMAX_DPP_STAGE(0xB1);
        ARGMAX_DPP_STAGE(0x4E);
        ARGMAX_DPP_STAGE(0x141);
        ARGMAX_DPP_STAGE(0x140);
        {
            const float ov = __shfl_xor(bv, 16);
            const int   oi = __shfl_xor(bi, 16);
            if (ov > bv || (ov == bv && oi < bi)) { bv = ov; bi = oi; }
        }
        if (pass == 0) { v1 = bv; i1 = bi; }
        else if (pass == 1) { v2 = bv; i2 = bi; }
        else { v3 = bv; i3 = bi; }
        if (sl == bi) lv = -1.f;
    }
    const float inv_ssum = 1.0f / (v1 + v2 + v3 + 1e-6f);

    // ================= sim + slot softmax (first consumption of m_r/m_i) ====
    float sims[8];
#pragma unroll
    for (int k = 0; k < 8; ++k) {
        float p = m_r[k].x * q4r.x + m_r[k].y * q4r.y + m_r[k].z * q4r.z + m_r[k].w * q4r.w
                + m_i[k].x * q4i.x + m_i[k].y * q4i.y + m_i[k].z * q4i.z + m_i[k].w * q4i.w;
        sims[k] = red16_dpp(p);   // sum over d within the 16-lane group
    }
    float mx = sims[0];
#pragma unroll
    for (int k = 1; k < 8; ++k) mx = fmaxf(mx, sims[k]);
    mx = fmaxf(mx, __shfl_xor(mx, 16));
    mx = fmaxf(mx, __shfl_xor(mx, 32));
    float attn[8];
    float asum = 0.f;
#pragma unroll
    for (int k = 0; k < 8; ++k) { attn[k] = __expf(sims[k] - mx); asum += attn[k]; }
    asum += __shfl_xor(asum, 16);
    asum += __shfl_xor(asum, 32);
    const float ainv = 1.0f / asum;

    // ---- read = attn @ mem ----
    float4 rr = {0.f, 0.f, 0.f, 0.f}, ri = {0.f, 0.f, 0.f, 0.f};
#pragma unroll
    for (int k = 0; k < 8; ++k) {
        const float a = attn[k] * ainv;
        rr.x = fmaf(a, m_r[k].x, rr.x); rr.y = fmaf(a, m_r[k].y, rr.y);
        rr.z = fmaf(a, m_r[k].z, rr.z); rr.w = fmaf(a, m_r[k].w, rr.w);
        ri.x = fmaf(a, m_i[k].x, ri.x); ri.y = fmaf(a, m_i[k].y, ri.y);
        ri.z = fmaf(a, m_i[k].z, ri.z); ri.w = fmaf(a, m_i[k].w, ri.w);
    }
    rr.x += __shfl_xor(rr.x, 16); rr.y += __shfl_xor(rr.y, 16);
    rr.z += __shfl_xor(rr.z, 16); rr.w += __shfl_xor(rr.w, 16);
    rr.x += __shfl_xor(rr.x, 32); rr.y += __shfl_xor(rr.y, 32);
    rr.z += __shfl_xor(rr.z, 32); rr.w += __shfl_xor(rr.w, 32);
    ri.x += __shfl_xor(ri.x, 16); ri.y += __shfl_xor(ri.y, 16);
    ri.z += __shfl_xor(ri.z, 16); ri.w += __shfl_xor(ri.w, 16);
    ri.x += __shfl_xor(ri.x, 32); ri.y += __shfl_xor(ri.y, 32);
    ri.z += __shfl_xor(ri.z, 32); ri.w += __shfl_xor(ri.w, 32);
    if (g == 0) {
        ((float4*)o_read_r)[b * 16 + q] = rr;
        ((float4*)o_read_i)[b * 16 + q] = ri;
    }

    // ---- blended write + dual LayerNorm (single pass sum/sumsq) + store ----
    const float4 gr  = ((const float4*)g_r)[q];
    const float4 br  = ((const float4*)b_r)[q];
    const float4 gi  = ((const float4*)g_i)[q];
    const float4 bi4 = ((const float4*)b_i)[q];
    float4* onr = (float4*)o_next_r + (size_t)b * 512;
    float4* oni = (float4*)o_next_i + (size_t)b * 512;

#pragma unroll
    for (int k = 0; k < 8; ++k) {
        const int s = k * 4 + g;
        const float sp = (s == i1) ? v1 : (s == i2) ? v2 : (s == i3) ? v3 : 0.f;
        const float eu = wgate * sp * inv_ssum;
        const float om = 1.f - eu;

        float4 xr, xi;
        xr.x = om * m_r[k].x + eu * q4r.x;
        xr.y = om * m_r[k].y + eu * q4r.y;
        xr.z = om * m_r[k].z + eu * q4r.z;
        xr.w = om * m_r[k].w + eu * q4r.w;
        xi.x = om * m_i[k].x + eu * q4i.x;
        xi.y = om * m_i[k].y + eu * q4i.y;
        xi.z = om * m_i[k].z + eu * q4i.z;
        xi.w = om * m_i[k].w + eu * q4i.w;

        float sr = (xr.x + xr.y) + (xr.z + xr.w);
        float si = (xi.x + xi.y) + (xi.z + xi.w);
        float qr = xr.x * xr.x; qr = fmaf(xr.y, xr.y, qr); qr = fmaf(xr.z, xr.z, qr); qr = fmaf(xr.w, xr.w, qr);
        float qi = xi.x * xi.x; qi = fmaf(xi.y, xi.y, qi); qi = fmaf(xi.z, xi.z, qi); qi = fmaf(xi.w, xi.w, qi);

        // within-16 reductions entirely on the VALU (no LDS traffic)
        sr = red16_dpp(sr);
        si = red16_dpp(si);
        qr = red16_dpp(qr);
        qi = red16_dpp(qi);

        const float mr_ = sr * (1.f / 64.f);
        const float mi_ = si * (1.f / 64.f);
        const float vr  = qr * (1.f / 64.f) - mr_ * mr_;
        const float vi  = qi * (1.f / 64.f) - mi_ * mi_;
        const float ar  = rsqrtf(vr + 1e-6f);
        const float ai  = rsqrtf(vi + 1e-6f);
        const float cr  = -mr_ * ar;
        const float ci  = -mi_ * ai;

        float4 yr, yi;
        yr.x = fmaf(fmaf(xr.x, ar, cr), gr.x, br.x);
        yr.y = fmaf(fmaf(xr.y, ar, cr), gr.y, br.y);
        yr.z = fmaf(fmaf(xr.z, ar, cr), gr.z, br.z);
        yr.w = fmaf(fmaf(xr.w, ar, cr), gr.w, br.w);
        yi.x = fmaf(fmaf(xi.x, ai, ci), gi.x, bi4.x);
        yi.y = fmaf(fmaf(xi.y, ai, ci), gi.y, bi4.y);
        yi.z = fmaf(fmaf(xi.z, ai, ci), gi.z, bi4.z);
        yi.w = fmaf(fmaf(xi.w, ai, ci), gi.w, bi4.w);
        onr[k * 64 + l] = yr;
        oni[k * 64 + l] = yi;
    }
}

// deterministic fixed-order reduction of the 16384 per-row entropy partials
__global__ __launch_bounds__(1024) void ent_reduce(const float* __restrict__ ws_ent,
                                                   float* __restrict__ o_ent)
{
    __shared__ float red[1024];
    const int t = threadIdx.x;
    float s = 0.f;
    for (int i = t; i < Bn; i += 1024) s += ws_ent[i];
    red[t] = s;
    __syncthreads();
    for (int st = 512; st > 0; st >>= 1) {
        if (t < st) red[t] += red[t + st];
        __syncthreads();
    }
    if (t == 0) o_ent[0] = red[0] * (1.0f / (float)Bn);
}

extern "C" void kernel_launch(void* const* d_in, const int* in_sizes, int n_in,
                              void* d_out, int out_size, void* d_ws, size_t ws_size,
                              hipStream_t stream)
{
    const float* gw_r  = (const float*)d_in[0];
    const float* gw_i  = (const float*)d_in[1];
    const float* mem_r = (const float*)d_in[2];
    const float* mem_i = (const float*)d_in[3];
    const float* Wg    = (const float*)d_in[4];
    const float* bg    = (const float*)d_in[5];
    const float* Wa    = (const float*)d_in[6];
    const float* ba    = (const float*)d_in[7];
    const float* g_r   = (const float*)d_in[8];
    const float* b_r   = (const float*)d_in[9];
    const float* g_i   = (const float*)d_in[10];
    const float* b_i   = (const float*)d_in[11];

    float* out = (float*)d_out;
    const size_t nBD  = (size_t)Bn * Dn;         // 1048576
    const size_t nBSD = (size_t)Bn * Sn * Dn;    // 33554432
    float* o_read_r = out;
    float* o_read_i = out + nBD;
    float* o_next_r = out + 2 * nBD;
    float* o_next_i = out + 2 * nBD + nBSD;
    float* o_ent    = out + 2 * nBD + 2 * nBSD;

    float* ws_ent = (float*)d_ws;   // Bn floats of scratch

    amem_fwd<<<Bn / 4, 256, 0, stream>>>(
        gw_r, gw_i, mem_r, mem_i, Wg, bg, Wa, ba, g_r, b_r, g_i, b_i,
        o_read_r, o_read_i, o_next_r, o_next_i, ws_ent);
    ent_reduce<<<1, 1024, 0, stream>>>(ws_ent, o_ent);
}